// Round 1
// baseline (656.181 us; speedup 1.0000x reference)
//
#include <hip/hip_runtime.h>

// SuperExpertMoE — round 1: dense bf16-MFMA baseline.
// Pipeline: gate -> finalize(loss) -> cast x/w1/sw1 -> build w2cat -> up GEMM (silu*combine) -> down GEMM (alpha*out+beta*x).
// Dense: all 9 "experts" (8 routed + 1 shared) computed for all tokens; combine weight (0 for unrouted) folded into H.

#define TOKS 4096
#define CD 2048
#define FD 1408
#define NE 9
#define FCAT 12672   // 9*1408

typedef unsigned short u16;
typedef float f32x4 __attribute__((ext_vector_type(4)));
typedef __bf16 bf16x8 __attribute__((ext_vector_type(8)));

__device__ __forceinline__ u16 f2bf(float f) {
  unsigned u = __float_as_uint(f);
  u += 0x7fffu + ((u >> 16) & 1u);   // RNE
  return (u16)(u >> 16);
}

// ---------------- gating: one wave per token ----------------
__global__ __launch_bounds__(256) void gate_kernel(
    const float* __restrict__ x, const float* __restrict__ gw,
    float* __restrict__ combine, float* __restrict__ part)
{
  const int lane = threadIdx.x & 63;
  const int wave = threadIdx.x >> 6;
  const int n = blockIdx.x * 4 + wave;
  const float* xr = x + (size_t)n * CD;
  float p[8] = {0,0,0,0,0,0,0,0};
#pragma unroll
  for (int it = 0; it < 8; ++it) {
    const int idx = it * 256 + lane * 4;
    const float4 xv = *(const float4*)(xr + idx);
#pragma unroll
    for (int e = 0; e < 8; ++e) {
      const float4 gv = *(const float4*)(gw + e * CD + idx);
      p[e] += xv.x * gv.x + xv.y * gv.y + xv.z * gv.z + xv.w * gv.w;
    }
  }
#pragma unroll
  for (int e = 0; e < 8; ++e) {
#pragma unroll
    for (int m = 32; m > 0; m >>= 1) p[e] += __shfl_xor(p[e], m, 64);
  }
  float mx = p[0];
#pragma unroll
  for (int e = 1; e < 8; ++e) mx = fmaxf(mx, p[e]);
  float s = 0.f, pr[8];
#pragma unroll
  for (int e = 0; e < 8; ++e) { pr[e] = __expf(p[e] - mx); s += pr[e]; }
  const float inv = 1.f / s;
#pragma unroll
  for (int e = 0; e < 8; ++e) pr[e] *= inv;
  const float lse = mx + __logf(s);
  int i1 = 0;
#pragma unroll
  for (int e = 1; e < 8; ++e) if (pr[e] > pr[i1]) i1 = e;   // strict > : jax tie-break (lowest index)
  int i2 = (i1 == 0) ? 1 : 0;
#pragma unroll
  for (int e = 0; e < 8; ++e) if (e != i1 && pr[e] > pr[i2]) i2 = e;
  const float rs = 1.f / (pr[i1] + pr[i2]);

  __shared__ float pl[4][12];
  if (lane == 0) {
    float* cr = combine + (size_t)n * 16;
#pragma unroll
    for (int e = 0; e < 8; ++e) cr[e] = 0.f;
    cr[i1] = pr[i1] * rs;
    cr[i2] = pr[i2] * rs;
    cr[8] = 1.0f;                       // shared expert weight
#pragma unroll
    for (int e = 0; e < 8; ++e) pl[wave][e] = pr[e];
    pl[wave][8] = lse * lse;
  }
  __syncthreads();
  if (threadIdx.x < 9)
    part[(size_t)blockIdx.x * 16 + threadIdx.x] =
        pl[0][threadIdx.x] + pl[1][threadIdx.x] + pl[2][threadIdx.x] + pl[3][threadIdx.x];
}

// deterministic tree reduce of 1024 per-block partials -> loss scalar
__global__ void finalize_kernel(const float* __restrict__ part, float* __restrict__ loss_out)
{
  __shared__ float sm[256][10];
  float loc[9] = {0,0,0,0,0,0,0,0,0};
  for (int b = threadIdx.x; b < 1024; b += 256)
#pragma unroll
    for (int c = 0; c < 9; ++c) loc[c] += part[(size_t)b * 16 + c];
#pragma unroll
  for (int c = 0; c < 9; ++c) sm[threadIdx.x][c] = loc[c];
  __syncthreads();
  for (int off = 128; off > 0; off >>= 1) {
    if (threadIdx.x < off)
#pragma unroll
      for (int c = 0; c < 9; ++c) sm[threadIdx.x][c] += sm[threadIdx.x + off][c];
    __syncthreads();
  }
  if (threadIdx.x == 0) {
    float aux = 0.f;
#pragma unroll
    for (int e = 0; e < 8; ++e) { const float m = sm[0][e] * (1.f / TOKS); aux += m * m; }
    const float z = sm[0][8] * (1.f / TOKS);
    loss_out[0] = 0.01f * aux + 0.001f * z;
  }
}

// ---------------- casts ----------------
__global__ void cast4_kernel(const float4* __restrict__ in, u16* __restrict__ out, int n4)
{
  int i = blockIdx.x * blockDim.x + threadIdx.x;
  const int stride = gridDim.x * blockDim.x;
  for (; i < n4; i += stride) {
    const float4 v = in[i];
    ushort4 o;
    o.x = f2bf(v.x); o.y = f2bf(v.y); o.z = f2bf(v.z); o.w = f2bf(v.w);
    *(ushort4*)(out + (size_t)i * 4) = o;
  }
}

// w2cat[c][e*FD+f] = w2[e][c][f] (e<8) or sw2[0][c][f] (e==8), cast to bf16
__global__ void w2cat_kernel(const float* __restrict__ w2, const float* __restrict__ sw2,
                             u16* __restrict__ out)
{
  const int total4 = NE * CD * (FD / 4);
  int i = blockIdx.x * blockDim.x + threadIdx.x;
  const int stride = gridDim.x * blockDim.x;
  for (; i < total4; i += stride) {
    const int e = i / (CD * (FD / 4));
    const int r = i % (CD * (FD / 4));
    const int c = r / (FD / 4);
    const int f4 = r % (FD / 4);
    const float4 v = (e < 8)
        ? *(const float4*)(w2 + ((size_t)e * CD + c) * FD + (size_t)f4 * 4)
        : *(const float4*)(sw2 + (size_t)c * FD + (size_t)f4 * 4);
    ushort4 o; o.x = f2bf(v.x); o.y = f2bf(v.y); o.z = f2bf(v.z); o.w = f2bf(v.w);
    *(ushort4*)(out + (size_t)c * FCAT + (size_t)e * FD + (size_t)f4 * 4) = o;
  }
}

// ---------------- GEMM (m97-style): A[M][K] x B[N][K]^T, 128x128 tile, BK=64 ----------------
// MODE 0: up-proj  -> outH[row][e*FD+col] = bf16(combine[row][e] * silu(acc))
// MODE 1: down-proj-> outY[row][col] = alpha[col]*acc + beta[col]*x[row][col]
template<int MODE>
__global__ __launch_bounds__(256, 2) void gemm_bt(
    const u16* __restrict__ A, const u16* __restrict__ B, const int K,
    u16* __restrict__ outH, float* __restrict__ outY,
    const float* __restrict__ combine,
    const float* __restrict__ alpha, const float* __restrict__ beta,
    const float* __restrict__ xres)
{
  __shared__ __attribute__((aligned(16))) u16 smA[128 * 64];
  __shared__ __attribute__((aligned(16))) u16 smB[128 * 64];
  const int tid = threadIdx.x;
  const int lane = tid & 63;
  const int wave = tid >> 6;
  const int wr = wave >> 1, wc = wave & 1;
  const int m0 = blockIdx.x * 128;
  const int n0 = blockIdx.y * 128;
  const int e = blockIdx.z;
  const u16* Bp = (MODE == 0) ? (B + (size_t)e * FD * CD) : B;

  const int sub_r = lane >> 3;          // 0..7 : row within 8-row chunk
  const int sub_c = (lane & 7) << 3;    // 0,8,..,56 : col (elements)

  f32x4 acc[4][4] = {};

  const int nkt = K >> 6;
  for (int kt = 0; kt < nkt; ++kt) {
    const int k0 = kt << 6;
#pragma unroll
    for (int r = 0; r < 4; ++r) {
      const int ch = (wave << 2) + r;   // 16 chunks of 1KB per tile
      const u16* ga = A + (size_t)(m0 + ch * 8 + sub_r) * K + k0 + sub_c;
      const u16* gb = Bp + (size_t)(n0 + ch * 8 + sub_r) * K + k0 + sub_c;
      __builtin_amdgcn_global_load_lds((const __attribute__((address_space(1))) void*)ga,
                                       (__attribute__((address_space(3))) void*)(smA + ch * 512),
                                       16, 0, 0);
      __builtin_amdgcn_global_load_lds((const __attribute__((address_space(1))) void*)gb,
                                       (__attribute__((address_space(3))) void*)(smB + ch * 512),
                                       16, 0, 0);
    }
    asm volatile("s_waitcnt vmcnt(0)" ::: "memory");
    __syncthreads();
#pragma unroll
    for (int kk = 0; kk < 2; ++kk) {
      const int ko = (kk << 5) + ((lane >> 4) << 3);
      bf16x8 af[4], bfv[4];
#pragma unroll
      for (int i = 0; i < 4; ++i)
        af[i] = *(const bf16x8*)(smA + ((wr * 64 + i * 16 + (lane & 15)) << 6) + ko);
#pragma unroll
      for (int j = 0; j < 4; ++j)
        bfv[j] = *(const bf16x8*)(smB + ((wc * 64 + j * 16 + (lane & 15)) << 6) + ko);
#pragma unroll
      for (int i = 0; i < 4; ++i)
#pragma unroll
        for (int j = 0; j < 4; ++j)
          acc[i][j] = __builtin_amdgcn_mfma_f32_16x16x32_bf16(af[i], bfv[j], acc[i][j], 0, 0, 0);
    }
    __syncthreads();
  }

  // epilogue — C/D layout: col = lane&15, row = (lane>>4)*4 + q (m89-verified)
#pragma unroll
  for (int i = 0; i < 4; ++i) {
    const int rb = m0 + wr * 64 + i * 16 + ((lane >> 4) << 2);
#pragma unroll
    for (int j = 0; j < 4; ++j) {
      const int col = n0 + wc * 64 + j * 16 + (lane & 15);
#pragma unroll
      for (int q = 0; q < 4; ++q) {
        const int row = rb + q;
        const float v = acc[i][j][q];
        if (MODE == 0) {
          const float sc = combine[(size_t)row * 16 + e];
          const float h = sc * v * (1.f / (1.f + __expf(-v)));
          outH[(size_t)row * FCAT + (size_t)e * FD + col] = f2bf(h);
        } else {
          outY[(size_t)row * CD + col] =
              alpha[col] * v + beta[col] * xres[(size_t)row * CD + col];
        }
      }
    }
  }
}

extern "C" void kernel_launch(void* const* d_in, const int* in_sizes, int n_in,
                              void* d_out, int out_size, void* d_ws, size_t ws_size,
                              hipStream_t stream)
{
  (void)in_sizes; (void)n_in; (void)out_size; (void)ws_size;
  const float* x     = (const float*)d_in[0];
  const float* gw    = (const float*)d_in[1];
  const float* w1    = (const float*)d_in[2];
  const float* w2    = (const float*)d_in[3];
  const float* sw1   = (const float*)d_in[4];
  const float* sw2   = (const float*)d_in[5];
  const float* alpha = (const float*)d_in[6];
  const float* beta  = (const float*)d_in[7];
  float* out = (float*)d_out;

  // workspace layout (~215 MB total)
  char* ws = (char*)d_ws;
  float* combine = (float*)(ws + 0);           // 4096*16*4   = 256 KB
  float* part    = (float*)(ws + 262144);      // 1024*16*4   = 64 KB
  u16*   xb      = (u16*)(ws + 327680);        // 4096*2048*2 = 16 MB
  u16*   w1b     = (u16*)(ws + 17104896);      // 9*1408*2048*2 = 51.9 MB
  u16*   w2c     = (u16*)(ws + 69009408);      // 2048*12672*2  = 51.9 MB
  u16*   hcat    = (u16*)(ws + 120913920);     // 4096*12672*2  = 103.8 MB

  gate_kernel<<<1024, 256, 0, stream>>>(x, gw, combine, part);
  finalize_kernel<<<1, 256, 0, stream>>>(part, out + (size_t)TOKS * CD);
  cast4_kernel<<<1024, 256, 0, stream>>>((const float4*)x, xb, TOKS * CD / 4);
  cast4_kernel<<<2048, 256, 0, stream>>>((const float4*)w1, w1b, 8 * FD * CD / 4);
  cast4_kernel<<<1024, 256, 0, stream>>>((const float4*)sw1, w1b + (size_t)8 * FD * CD, FD * CD / 4);
  w2cat_kernel<<<2048, 256, 0, stream>>>(w2, sw2, w2c);
  gemm_bt<0><<<dim3(32, 11, 9), 256, 0, stream>>>(xb, w1b, CD, hcat, nullptr, combine, nullptr, nullptr, nullptr);
  gemm_bt<1><<<dim3(32, 16, 1), 256, 0, stream>>>(hcat, w2c, FCAT, nullptr, out, nullptr, alpha, beta, x);
}